// Round 1
// 7571.452 us; speedup vs baseline: 1.5078x; 1.5078x over previous
//
#include <hip/hip_runtime.h>
#include <math.h>

#define D 768
#define T_CTX 1024
#define NH 6
#define HS 128
#define FFD 3072
#define NL 6
#define VOCAB 32000
#define ROWS 4096   // B*T

typedef __attribute__((ext_vector_type(8))) short short8;   // 8 bf16 (4 VGPRs)
typedef __attribute__((ext_vector_type(4))) float f32x4;

// ---------------- fp32 -> bf16 split helpers ------------------------------
__device__ __forceinline__ unsigned bfround(float f) {
    unsigned u = __builtin_bit_cast(unsigned, f);
    return (u + 0x7fffu + ((u >> 16) & 1u)) >> 16;   // RNE, bits in low 16
}
// split a,b into packed-hi (truncated bf16) and packed-lo (RNE bf16 of residual)
__device__ __forceinline__ void split2(float a, float b, unsigned &hi, unsigned &lo) {
    unsigned ua = __builtin_bit_cast(unsigned, a) & 0xffff0000u;
    unsigned ub = __builtin_bit_cast(unsigned, b) & 0xffff0000u;
    hi = (ua >> 16) | ub;
    float la = a - __builtin_bit_cast(float, ua);
    float lb = b - __builtin_bit_cast(float, ub);
    lo = bfround(la) | (bfround(lb) << 16);
}

// ---------------- embedding: x[b,t,:] = tok_emb[idx[b,t]] + pos_emb[t] ----
__global__ __launch_bounds__(192) void embed_kernel(
    const int* __restrict__ idx, const float* __restrict__ tok,
    const float* __restrict__ pos, float* __restrict__ x)
{
    int row = blockIdx.x;           // b*T + t
    int t = row & (T_CTX - 1);
    int tk = idx[row];
    const float4* t4 = (const float4*)(tok + (long)tk * D);
    const float4* p4 = (const float4*)(pos + (long)t * D);
    float4* x4 = (float4*)(x + (long)row * D);
    int c = threadIdx.x;            // 0..191  (768/4)
    float4 a = t4[c], b = p4[c];
    x4[c] = make_float4(a.x + b.x, a.y + b.y, a.z + b.z, a.w + b.w);
}

// ---------------- layernorm (row of 768) ---------------------------------
__global__ __launch_bounds__(256) void ln_kernel(
    const float* __restrict__ x, const float* __restrict__ g,
    const float* __restrict__ b, float* __restrict__ out)
{
    int row = blockIdx.x;
    const float* xr = x + (long)row * D;
    int tid = threadIdx.x;
    float v0 = xr[tid], v1 = xr[tid + 256], v2 = xr[tid + 512];
    float s  = v0 + v1 + v2;
    float s2 = v0 * v0 + v1 * v1 + v2 * v2;
    #pragma unroll
    for (int off = 32; off >= 1; off >>= 1) {
        s  += __shfl_xor(s, off);
        s2 += __shfl_xor(s2, off);
    }
    __shared__ float ws_[4], ws2_[4];
    int wid = tid >> 6, lane = tid & 63;
    if (lane == 0) { ws_[wid] = s; ws2_[wid] = s2; }
    __syncthreads();
    s  = ws_[0] + ws_[1] + ws_[2] + ws_[3];
    s2 = ws2_[0] + ws2_[1] + ws2_[2] + ws2_[3];
    float mu  = s * (1.0f / D);
    float var = s2 * (1.0f / D) - mu * mu;
    float rs  = rsqrtf(var + 1e-5f);
    float* orow = out + (long)row * D;
    orow[tid]       = (v0 - mu) * rs * g[tid]       + b[tid];
    orow[tid + 256] = (v1 - mu) * rs * g[tid + 256] + b[tid + 256];
    orow[tid + 512] = (v2 - mu) * rs * g[tid + 512] + b[tid + 512];
}

// ---------------- MFMA split-bf16 GEMM: C = A*B (+bias)(+res)(relu) ------
// A: [M,K] fp32 row-major lda (=K). B: [K,N] fp32 row-major ldb, per-z
// offset b_zstride. C columns offset by z*c_zoff (QKV heads).
// Tile 128x128, BK=32, 256 threads = 4 waves (2x2), each wave 64x64 out
// via 4x4 fragments of v_mfma_f32_16x16x32_bf16, 3 MFMAs per fragment
// (hi*hi + hi*lo + lo*hi) for near-fp32 accuracy.
// LDS: As/Bs[128 rows][64 bf16] (hi in k=0..31, lo in k=32..63), row
// stride 128 B, XOR swizzle byte ^= (row&7)<<4 -> conflict-free b128.
__global__ __launch_bounds__(256) void gemm_kernel(
    const float* __restrict__ A, int lda,
    const float* __restrict__ Bm, int ldb, long b_zstride,
    float* __restrict__ C, int ldc, int c_zoff,
    const float* __restrict__ bias, const float* __restrict__ res,
    int K, int relu)
{
    const float* B = Bm + (long)blockIdx.z * b_zstride;
    int bm = blockIdx.y * 128;
    int bn = blockIdx.x * 128;
    int zoff = blockIdx.z * c_zoff;
    __shared__ short As[128 * 64];   // 16 KB
    __shared__ short Bs[128 * 64];   // 16 KB
    int tid = threadIdx.x;
    int lane = tid & 63, w = tid >> 6;
    int wm = w >> 1, wn = w & 1;
    int cc = lane & 15, g = lane >> 4;

    f32x4 acc[4][4];
    {
        f32x4 zf = {0.f, 0.f, 0.f, 0.f};
        #pragma unroll
        for (int i = 0; i < 4; ++i)
            #pragma unroll
            for (int j = 0; j < 4; ++j) acc[i][j] = zf;
    }

    // B staging: thread -> (col n, k-half)
    int n_b = tid & 127;
    int kh_b = (tid >> 7) << 4;          // 0 or 16
    const float* Agb = A + (long)bm * lda;

    for (int k0 = 0; k0 < K; k0 += 32) {
        // ---- global loads into regs (A: 4 float4, B: 16 strided scalars)
        float4 a4[4];
        #pragma unroll
        for (int i = 0; i < 4; ++i) {
            int f = tid + i * 256;       // 0..1023 over 128 rows x 8 float4
            int r = f >> 3, kc = (f & 7) << 2;
            a4[i] = *(const float4*)(Agb + (long)r * lda + k0 + kc);
        }
        float bvv[16];
        const float* Bg = B + (long)(k0 + kh_b) * ldb + bn + n_b;
        #pragma unroll
        for (int j = 0; j < 16; ++j) bvv[j] = Bg[(long)j * ldb];

        __syncthreads();                 // prior iteration's ds_reads done

        // ---- split + LDS writes (swizzled)
        #pragma unroll
        for (int i = 0; i < 4; ++i) {
            int f = tid + i * 256;
            int r = f >> 3, kc = (f & 7) << 2;
            unsigned h0, l0, h1, l1;
            split2(a4[i].x, a4[i].y, h0, l0);
            split2(a4[i].z, a4[i].w, h1, l1);
            int xr = (r & 7) << 4;
            int ah_addr = ((r << 7) + (kc << 1)) ^ xr;
            *(int2*)((char*)As + ah_addr)        = make_int2((int)h0, (int)h1);
            *(int2*)((char*)As + (ah_addr ^ 64)) = make_int2((int)l0, (int)l1);
        }
        {
            unsigned hp[8], lp[8];
            #pragma unroll
            for (int j = 0; j < 8; ++j) split2(bvv[2*j], bvv[2*j+1], hp[j], lp[j]);
            int basen = (n_b << 7) + (kh_b << 1);
            int xr = (n_b & 7) << 4;
            *(int4*)((char*)Bs + ((basen     ) ^ xr)) = make_int4(hp[0], hp[1], hp[2], hp[3]);
            *(int4*)((char*)Bs + ((basen + 16) ^ xr)) = make_int4(hp[4], hp[5], hp[6], hp[7]);
            *(int4*)((char*)Bs + ((basen + 64) ^ xr)) = make_int4(lp[0], lp[1], lp[2], lp[3]);
            *(int4*)((char*)Bs + ((basen + 80) ^ xr)) = make_int4(lp[4], lp[5], lp[6], lp[7]);
        }
        __syncthreads();

        // ---- fragment reads (ds_read_b128, conflict-free via swizzle)
        short8 ah[4], al[4], bh[4], bl[4];
        #pragma unroll
        for (int mi = 0; mi < 4; ++mi) {
            int r = (wm << 6) + (mi << 4) + cc;
            int addr = (((r << 7) + (g << 4))) ^ ((r & 7) << 4);
            ah[mi] = *(const short8*)((const char*)As + addr);
            al[mi] = *(const short8*)((const char*)As + (addr ^ 64));
        }
        #pragma unroll
        for (int ni = 0; ni < 4; ++ni) {
            int r = (wn << 6) + (ni << 4) + cc;
            int addr = (((r << 7) + (g << 4))) ^ ((r & 7) << 4);
            bh[ni] = *(const short8*)((const char*)Bs + addr);
            bl[ni] = *(const short8*)((const char*)Bs + (addr ^ 64));
        }

        // ---- 48 MFMAs: hi*hi + hi*lo + lo*hi
        #pragma unroll
        for (int mi = 0; mi < 4; ++mi)
            #pragma unroll
            for (int ni = 0; ni < 4; ++ni) {
                acc[mi][ni] = __builtin_amdgcn_mfma_f32_16x16x32_bf16(ah[mi], bh[ni], acc[mi][ni], 0, 0, 0);
                acc[mi][ni] = __builtin_amdgcn_mfma_f32_16x16x32_bf16(ah[mi], bl[ni], acc[mi][ni], 0, 0, 0);
                acc[mi][ni] = __builtin_amdgcn_mfma_f32_16x16x32_bf16(al[mi], bh[ni], acc[mi][ni], 0, 0, 0);
            }
    }

    // ---- epilogue: C/D layout col=lane&15, row=(lane>>4)*4+j (verified)
    #pragma unroll
    for (int mi = 0; mi < 4; ++mi) {
        int row0 = bm + (wm << 6) + (mi << 4) + (g << 2);
        #pragma unroll
        for (int ni = 0; ni < 4; ++ni) {
            int col = zoff + bn + (wn << 6) + (ni << 4) + cc;
            #pragma unroll
            for (int j = 0; j < 4; ++j) {
                long ci = (long)(row0 + j) * ldc + col;
                float vv = acc[mi][ni][j];
                if (bias) vv += bias[col];
                if (res)  vv += res[ci];
                if (relu) vv = fmaxf(vv, 0.f);
                C[ci] = vv;
            }
        }
    }
}

// ---------------- flash attention --------------------------------------
__global__ __launch_bounds__(256) void attn_kernel(
    const float* __restrict__ q, const float* __restrict__ k,
    const float* __restrict__ v, float* __restrict__ att)
{
    int bh = blockIdx.z;             // b*NH + h
    int b = bh / NH, hh = bh % NH;
    int t0 = blockIdx.x * 4;
    int tid = threadIdx.x;
    int w = tid >> 6, lane = tid & 63;
    int t = t0 + w;
    const float* qb = q + (long)b * T_CTX * D + hh * HS;
    const float* kb = k + (long)b * T_CTX * D + hh * HS;
    const float* vb = v + (long)b * T_CTX * D + hh * HS;
    __shared__ float Qs[4][HS];        // 2 KB
    __shared__ float Ks[64][HS + 1];   // 33 KB
    __shared__ float Vs[64][HS];       // 32 KB
    __shared__ float Ps[4][64];        // 1 KB
    for (int i = tid; i < 4 * HS; i += 256) {
        int r = i >> 7, c = i & 127;
        Qs[r][c] = qb[(long)(t0 + r) * D + c];
    }
    float m = -1e30f, l = 0.f, o0 = 0.f, o1 = 0.f;
    const float scale = 0.0883883476483184f;  // 1/sqrt(128)
    int ntiles = (t0 + 3) / 64 + 1;
    for (int tile = 0; tile < ntiles; ++tile) {
        int kt0 = tile * 64;
        __syncthreads();
        for (int i = tid; i < 64 * 32; i += 256) {
            int r = i >> 5, cq = (i & 31) << 2;
            float4 kv = *(const float4*)(kb + (long)(kt0 + r) * D + cq);
            Ks[r][cq + 0] = kv.x; Ks[r][cq + 1] = kv.y;
            Ks[r][cq + 2] = kv.z; Ks[r][cq + 3] = kv.w;
            *(float4*)&Vs[r][cq] = *(const float4*)(vb + (long)(kt0 + r) * D + cq);
        }
        __syncthreads();
        if (kt0 <= t) {
            int s = kt0 + lane;
            float dot = 0.f;
            #pragma unroll
            for (int c = 0; c < HS; ++c) dot = fmaf(Qs[w][c], Ks[lane][c], dot);
            float sc = (s <= t) ? dot * scale : -1e30f;
            float mt = sc;
            #pragma unroll
            for (int off = 32; off >= 1; off >>= 1) mt = fmaxf(mt, __shfl_xor(mt, off));
            float mnew = fmaxf(m, mt);
            float p = (s <= t) ? __expf(sc - mnew) : 0.f;
            float ls = p;
            #pragma unroll
            for (int off = 32; off >= 1; off >>= 1) ls += __shfl_xor(ls, off);
            float alpha = __expf(m - mnew);
            l = l * alpha + ls;
            o0 *= alpha; o1 *= alpha;
            m = mnew;
            Ps[w][lane] = p;
            #pragma unroll 8
            for (int ss = 0; ss < 64; ++ss) {
                float pv = Ps[w][ss];
                o0 = fmaf(pv, Vs[ss][lane], o0);
                o1 = fmaf(pv, Vs[ss][lane + 64], o1);
            }
        }
    }
    float inv = 1.0f / l;
    float* ar = att + (long)(b * T_CTX + t) * D + hh * HS;
    ar[lane]      = o0 * inv;
    ar[lane + 64] = o1 * inv;
}

// ---------------- launch -------------------------------------------------
extern "C" void kernel_launch(void* const* d_in, const int* in_sizes, int n_in,
                              void* d_out, int out_size, void* d_ws, size_t ws_size,
                              hipStream_t stream) {
    (void)in_sizes; (void)n_in; (void)out_size; (void)ws_size;
    const int*   idx     = (const int*)  d_in[0];
    const float* tok_emb = (const float*)d_in[1];
    const float* pos_emb = (const float*)d_in[2];
    const float* wq      = (const float*)d_in[3];
    const float* wk      = (const float*)d_in[4];
    const float* wv      = (const float*)d_in[5];
    const float* wo      = (const float*)d_in[6];
    const float* bo      = (const float*)d_in[7];
    const float* w1      = (const float*)d_in[8];
    const float* b1      = (const float*)d_in[9];
    const float* w2      = (const float*)d_in[10];
    const float* b2      = (const float*)d_in[11];
    const float* g1      = (const float*)d_in[12];
    const float* be1     = (const float*)d_in[13];
    const float* g2      = (const float*)d_in[14];
    const float* be2     = (const float*)d_in[15];
    const float* wlm     = (const float*)d_in[16];
    const float* blm     = (const float*)d_in[17];
    float* out = (float*)d_out;

    const long SZ = (long)ROWS * D;     // 3,145,728 floats
    float* ws   = (float*)d_ws;
    float* x    = ws;                   // [4096, 768]
    float* h    = ws + SZ;              // [4096, 768]
    float* q    = ws + 2 * SZ;          // [4096, 768]
    float* kbuf = ws + 3 * SZ;
    float* vbuf = ws + 4 * SZ;
    float* att  = ws + 5 * SZ;
    float* ff   = q;                    // [4096, 3072] reuses q..att (exact fit)

    embed_kernel<<<ROWS, 192, 0, stream>>>(idx, tok_emb, pos_emb, x);

    for (int l = 0; l < NL; ++l) {
        ln_kernel<<<ROWS, 256, 0, stream>>>(x, g1 + l * D, be1 + l * D, h);

        dim3 gq(1, 32, NH);
        const long wsz = (long)NH * D * HS;   // per-layer q/k/v weight size
        gemm_kernel<<<gq, 256, 0, stream>>>(h, D, wq + (long)l * wsz, HS,
                                            (long)D * HS, q, D, HS,
                                            nullptr, nullptr, D, 0);
        gemm_kernel<<<gq, 256, 0, stream>>>(h, D, wk + (long)l * wsz, HS,
                                            (long)D * HS, kbuf, D, HS,
                                            nullptr, nullptr, D, 0);
        gemm_kernel<<<gq, 256, 0, stream>>>(h, D, wv + (long)l * wsz, HS,
                                            (long)D * HS, vbuf, D, HS,
                                            nullptr, nullptr, D, 0);

        attn_kernel<<<dim3(T_CTX / 4, 1, 4 * NH), 256, 0, stream>>>(q, kbuf, vbuf, att);

        // x = x + att @ wo + bo
        gemm_kernel<<<dim3(6, 32, 1), 256, 0, stream>>>(
            att, D, wo + (long)l * D * D, D, 0, x, D, 0,
            bo + l * D, x, D, 0);

        ln_kernel<<<ROWS, 256, 0, stream>>>(x, g2 + l * D, be2 + l * D, h);

        // ff = relu(h @ w1 + b1)
        gemm_kernel<<<dim3(24, 32, 1), 256, 0, stream>>>(
            h, D, w1 + (long)l * D * FFD, FFD, 0, ff, FFD, 0,
            b1 + (long)l * FFD, nullptr, D, 1);

        // x = x + ff @ w2 + b2
        gemm_kernel<<<dim3(6, 32, 1), 256, 0, stream>>>(
            ff, FFD, w2 + (long)l * FFD * D, D, 0, x, D, 0,
            b2 + l * D, x, FFD, 0);
    }

    // out = x @ wlm + blm
    gemm_kernel<<<dim3(VOCAB / 128, 32, 1), 256, 0, stream>>>(
        x, D, wlm, VOCAB, 0, out, VOCAB, 0, blm, nullptr, D, 0);
}

// Round 2
// 5096.078 us; speedup vs baseline: 2.2402x; 1.4857x over previous
//
#include <hip/hip_runtime.h>
#include <math.h>

#define D 768
#define T_CTX 1024
#define NH 6
#define HS 128
#define FFD 3072
#define NL 6
#define VOCAB 32000
#define ROWS 4096   // B*T

typedef __attribute__((ext_vector_type(8))) short short8;   // 8 bf16 (4 VGPRs)
typedef __attribute__((ext_vector_type(4))) float f32x4;

// ---------------- fp32 -> bf16 split helpers ------------------------------
__device__ __forceinline__ unsigned bfround(float f) {
    unsigned u = __builtin_bit_cast(unsigned, f);
    return (u + 0x7fffu + ((u >> 16) & 1u)) >> 16;   // RNE, bits in low 16
}
__device__ __forceinline__ void split2(float a, float b, unsigned &hi, unsigned &lo) {
    unsigned ua = __builtin_bit_cast(unsigned, a) & 0xffff0000u;
    unsigned ub = __builtin_bit_cast(unsigned, b) & 0xffff0000u;
    hi = (ua >> 16) | ub;
    float la = a - __builtin_bit_cast(float, ua);
    float lb = b - __builtin_bit_cast(float, ub);
    lo = bfround(la) | (bfround(lb) << 16);
}

// ---------------- embedding ----------------------------------------------
__global__ __launch_bounds__(192) void embed_kernel(
    const int* __restrict__ idx, const float* __restrict__ tok,
    const float* __restrict__ pos, float* __restrict__ x)
{
    int row = blockIdx.x;
    int t = row & (T_CTX - 1);
    int tk = idx[row];
    const float4* t4 = (const float4*)(tok + (long)tk * D);
    const float4* p4 = (const float4*)(pos + (long)t * D);
    float4* x4 = (float4*)(x + (long)row * D);
    int c = threadIdx.x;
    float4 a = t4[c], b = p4[c];
    x4[c] = make_float4(a.x + b.x, a.y + b.y, a.z + b.z, a.w + b.w);
}

// ---------------- layernorm ----------------------------------------------
__global__ __launch_bounds__(256) void ln_kernel(
    const float* __restrict__ x, const float* __restrict__ g,
    const float* __restrict__ b, float* __restrict__ out)
{
    int row = blockIdx.x;
    const float* xr = x + (long)row * D;
    int tid = threadIdx.x;
    float v0 = xr[tid], v1 = xr[tid + 256], v2 = xr[tid + 512];
    float s  = v0 + v1 + v2;
    float s2 = v0 * v0 + v1 * v1 + v2 * v2;
    #pragma unroll
    for (int off = 32; off >= 1; off >>= 1) {
        s  += __shfl_xor(s, off);
        s2 += __shfl_xor(s2, off);
    }
    __shared__ float ws_[4], ws2_[4];
    int wid = tid >> 6, lane = tid & 63;
    if (lane == 0) { ws_[wid] = s; ws2_[wid] = s2; }
    __syncthreads();
    s  = ws_[0] + ws_[1] + ws_[2] + ws_[3];
    s2 = ws2_[0] + ws2_[1] + ws2_[2] + ws2_[3];
    float mu  = s * (1.0f / D);
    float var = s2 * (1.0f / D) - mu * mu;
    float rs  = rsqrtf(var + 1e-5f);
    float* orow = out + (long)row * D;
    orow[tid]       = (v0 - mu) * rs * g[tid]       + b[tid];
    orow[tid + 256] = (v1 - mu) * rs * g[tid + 256] + b[tid + 256];
    orow[tid + 512] = (v2 - mu) * rs * g[tid + 512] + b[tid + 512];
}

// ---------------- MFMA split-bf16 GEMM -----------------------------------
// vt=0: C[row][zoff+col] normal. vt=1: writes V^T layout [b][z][d][t]
// (C index = ((b*NH+z)*HS+d)*T_CTX + t), float4 along t.
__global__ __launch_bounds__(256) void gemm_kernel(
    const float* __restrict__ A, int lda,
    const float* __restrict__ Bm, int ldb, long b_zstride,
    float* __restrict__ C, int ldc, int c_zoff,
    const float* __restrict__ bias, const float* __restrict__ res,
    int K, int relu, int vt)
{
    const float* B = Bm + (long)blockIdx.z * b_zstride;
    int bm = blockIdx.y * 128;
    int bn = blockIdx.x * 128;
    int zoff = blockIdx.z * c_zoff;
    __shared__ short As[128 * 64];
    __shared__ short Bs[128 * 64];
    int tid = threadIdx.x;
    int lane = tid & 63, w = tid >> 6;
    int wm = w >> 1, wn = w & 1;
    int cc = lane & 15, g = lane >> 4;

    f32x4 acc[4][4];
    {
        f32x4 zf = {0.f, 0.f, 0.f, 0.f};
        #pragma unroll
        for (int i = 0; i < 4; ++i)
            #pragma unroll
            for (int j = 0; j < 4; ++j) acc[i][j] = zf;
    }

    int n_b = tid & 127;
    int kh_b = (tid >> 7) << 4;
    const float* Agb = A + (long)bm * lda;

    for (int k0 = 0; k0 < K; k0 += 32) {
        float4 a4[4];
        #pragma unroll
        for (int i = 0; i < 4; ++i) {
            int f = tid + i * 256;
            int r = f >> 3, kc = (f & 7) << 2;
            a4[i] = *(const float4*)(Agb + (long)r * lda + k0 + kc);
        }
        float bvv[16];
        const float* Bg = B + (long)(k0 + kh_b) * ldb + bn + n_b;
        #pragma unroll
        for (int j = 0; j < 16; ++j) bvv[j] = Bg[(long)j * ldb];

        __syncthreads();

        #pragma unroll
        for (int i = 0; i < 4; ++i) {
            int f = tid + i * 256;
            int r = f >> 3, kc = (f & 7) << 2;
            unsigned h0, l0, h1, l1;
            split2(a4[i].x, a4[i].y, h0, l0);
            split2(a4[i].z, a4[i].w, h1, l1);
            int xr = (r & 7) << 4;
            int ah_addr = ((r << 7) + (kc << 1)) ^ xr;
            *(int2*)((char*)As + ah_addr)        = make_int2((int)h0, (int)h1);
            *(int2*)((char*)As + (ah_addr ^ 64)) = make_int2((int)l0, (int)l1);
        }
        {
            unsigned hp[8], lp[8];
            #pragma unroll
            for (int j = 0; j < 8; ++j) split2(bvv[2*j], bvv[2*j+1], hp[j], lp[j]);
            int basen = (n_b << 7) + (kh_b << 1);
            int xr = (n_b & 7) << 4;
            *(int4*)((char*)Bs + ((basen     ) ^ xr)) = make_int4(hp[0], hp[1], hp[2], hp[3]);
            *(int4*)((char*)Bs + ((basen + 16) ^ xr)) = make_int4(hp[4], hp[5], hp[6], hp[7]);
            *(int4*)((char*)Bs + ((basen + 64) ^ xr)) = make_int4(lp[0], lp[1], lp[2], lp[3]);
            *(int4*)((char*)Bs + ((basen + 80) ^ xr)) = make_int4(lp[4], lp[5], lp[6], lp[7]);
        }
        __syncthreads();

        short8 ah[4], al[4], bh[4], bl[4];
        #pragma unroll
        for (int mi = 0; mi < 4; ++mi) {
            int r = (wm << 6) + (mi << 4) + cc;
            int addr = (((r << 7) + (g << 4))) ^ ((r & 7) << 4);
            ah[mi] = *(const short8*)((const char*)As + addr);
            al[mi] = *(const short8*)((const char*)As + (addr ^ 64));
        }
        #pragma unroll
        for (int ni = 0; ni < 4; ++ni) {
            int r = (wn << 6) + (ni << 4) + cc;
            int addr = (((r << 7) + (g << 4))) ^ ((r & 7) << 4);
            bh[ni] = *(const short8*)((const char*)Bs + addr);
            bl[ni] = *(const short8*)((const char*)Bs + (addr ^ 64));
        }

        #pragma unroll
        for (int mi = 0; mi < 4; ++mi)
            #pragma unroll
            for (int ni = 0; ni < 4; ++ni) {
                acc[mi][ni] = __builtin_amdgcn_mfma_f32_16x16x32_bf16(ah[mi], bh[ni], acc[mi][ni], 0, 0, 0);
                acc[mi][ni] = __builtin_amdgcn_mfma_f32_16x16x32_bf16(ah[mi], bl[ni], acc[mi][ni], 0, 0, 0);
                acc[mi][ni] = __builtin_amdgcn_mfma_f32_16x16x32_bf16(al[mi], bh[ni], acc[mi][ni], 0, 0, 0);
            }
    }

    if (vt) {
        // write V^T: [b][z][d][t], t from A-row, d from column
        #pragma unroll
        for (int mi = 0; mi < 4; ++mi) {
            int r0 = bm + (wm << 6) + (mi << 4) + (g << 2);
            int bb = r0 >> 10, tt = r0 & 1023;
            #pragma unroll
            for (int ni = 0; ni < 4; ++ni) {
                int d = bn + (wn << 6) + (ni << 4) + cc;
                long ci = (((long)bb * NH + blockIdx.z) * HS + d) * T_CTX + tt;
                *(float4*)&C[ci] = make_float4(acc[mi][ni][0], acc[mi][ni][1],
                                               acc[mi][ni][2], acc[mi][ni][3]);
            }
        }
        return;
    }

    #pragma unroll
    for (int mi = 0; mi < 4; ++mi) {
        int row0 = bm + (wm << 6) + (mi << 4) + (g << 2);
        #pragma unroll
        for (int ni = 0; ni < 4; ++ni) {
            int col = zoff + bn + (wn << 6) + (ni << 4) + cc;
            #pragma unroll
            for (int j = 0; j < 4; ++j) {
                long ci = (long)(row0 + j) * ldc + col;
                float vv = acc[mi][ni][j];
                if (bias) vv += bias[col];
                if (res)  vv += res[ci];
                if (relu) vv = fmaxf(vv, 0.f);
                C[ci] = vv;
            }
        }
    }
}

// ---------------- MFMA flash attention -----------------------------------
// grid (T/64, B*NH). Block = 64 q-rows, 4 waves x 16 q-rows.
// Q,K split-bf16 (3-term QK^T); P bf16 (sum over rounded P); V split-bf16.
// vt input is V^T in [b][h][d][t] layout (from gemm vt=1).
__global__ __launch_bounds__(256) void attn_kernel(
    const float* __restrict__ q, const float* __restrict__ k,
    const float* __restrict__ vt, float* __restrict__ att)
{
    int z = blockIdx.y;               // b*NH + h
    int b = z / NH, hh = z % NH;
    int q0 = blockIdx.x << 6;
    int tid = threadIdx.x;
    int wv = tid >> 6, lane = tid & 63;
    int cc = lane & 15, g = lane >> 4;

    __shared__ short Ks_hi[64 * 128], Ks_lo[64 * 128];   // [kr][dim], 256B rows, slot^ (r&15)
    __shared__ short Vs_hi[128 * 64], Vs_lo[128 * 64];   // [d][k],   128B rows, slot^ (d&7)
    __shared__ short Ps[4 * 16 * 64];                    // per-wave [16q][64k], slot^ (q&7)

    const float* qbase = q  + (long)b * T_CTX * D + hh * HS;
    const float* kbase = k  + (long)b * T_CTX * D + hh * HS;
    const float* vbase = vt + (long)z * HS * T_CTX;

    // ---- stage Q tile into Ks buffers, pull Q fragments to registers ----
    #pragma unroll
    for (int i = 0; i < 8; ++i) {
        int idx = tid + (i << 8);           // 64 rows x 32 float4
        int r = idx >> 5, c4 = idx & 31;
        float4 a = *(const float4*)(qbase + (long)(q0 + r) * D + (c4 << 2));
        unsigned h0, l0, h1, l1;
        split2(a.x, a.y, h0, l0);
        split2(a.z, a.w, h1, l1);
        int byte = (r << 8) + ((((c4 >> 1) ^ (r & 15)) << 4) | ((c4 & 1) << 3));
        *(int2*)((char*)Ks_hi + byte) = make_int2((int)h0, (int)h1);
        *(int2*)((char*)Ks_lo + byte) = make_int2((int)l0, (int)l1);
    }
    __syncthreads();
    short8 qh[4], ql[4];
    {
        int r = (wv << 4) + cc;
        #pragma unroll
        for (int kf = 0; kf < 4; ++kf) {
            int addr = (r << 8) + ((((kf << 2) + g) ^ (r & 15)) << 4);
            qh[kf] = *(const short8*)((const char*)Ks_hi + addr);
            ql[kf] = *(const short8*)((const char*)Ks_lo + addr);
        }
    }

    f32x4 acc_o[8];
    {
        f32x4 zf = {0.f, 0.f, 0.f, 0.f};
        #pragma unroll
        for (int i = 0; i < 8; ++i) acc_o[i] = zf;
    }
    float m_[4] = {-1e30f, -1e30f, -1e30f, -1e30f};
    float l_[4] = {0.f, 0.f, 0.f, 0.f};
    const float scale = 0.08838834764831845f;  // 1/sqrt(128)

    int ntiles = (q0 >> 6) + 1;
    for (int tile = 0; tile < ntiles; ++tile) {
        int kt0 = tile << 6;
        __syncthreads();   // previous tile's reads (and Q-frag reads) done
        // ---- stage K tile [64][128] ----
        #pragma unroll
        for (int i = 0; i < 8; ++i) {
            int idx = tid + (i << 8);
            int r = idx >> 5, c4 = idx & 31;
            float4 a = *(const float4*)(kbase + (long)(kt0 + r) * D + (c4 << 2));
            unsigned h0, l0, h1, l1;
            split2(a.x, a.y, h0, l0);
            split2(a.z, a.w, h1, l1);
            int byte = (r << 8) + ((((c4 >> 1) ^ (r & 15)) << 4) | ((c4 & 1) << 3));
            *(int2*)((char*)Ks_hi + byte) = make_int2((int)h0, (int)h1);
            *(int2*)((char*)Ks_lo + byte) = make_int2((int)l0, (int)l1);
        }
        // ---- stage V^T tile [128 d][64 t] ----
        #pragma unroll
        for (int i = 0; i < 8; ++i) {
            int idx = tid + (i << 8);           // 128 rows x 16 float4
            int d = idx >> 4, c4 = idx & 15;
            float4 a = *(const float4*)(vbase + (long)d * T_CTX + kt0 + (c4 << 2));
            unsigned h0, l0, h1, l1;
            split2(a.x, a.y, h0, l0);
            split2(a.z, a.w, h1, l1);
            int byte = (d << 7) + ((((c4 >> 1) ^ (d & 7)) << 4) | ((c4 & 1) << 3));
            *(int2*)((char*)Vs_hi + byte) = make_int2((int)h0, (int)h1);
            *(int2*)((char*)Vs_lo + byte) = make_int2((int)l0, (int)l1);
        }
        __syncthreads();

        // ---- QK^T: S = Q.K^T  (wave's 16 q x 64 k) ----
        f32x4 s_acc[4];
        {
            f32x4 zf = {0.f, 0.f, 0.f, 0.f};
            #pragma unroll
            for (int i = 0; i < 4; ++i) s_acc[i] = zf;
        }
        #pragma unroll
        for (int kf = 0; kf < 4; ++kf) {
            #pragma unroll
            for (int nf = 0; nf < 4; ++nf) {
                int r = (nf << 4) + cc;
                int addr = (r << 8) + ((((kf << 2) + g) ^ (r & 15)) << 4);
                short8 kh = *(const short8*)((const char*)Ks_hi + addr);
                short8 kl = *(const short8*)((const char*)Ks_lo + addr);
                s_acc[nf] = __builtin_amdgcn_mfma_f32_16x16x32_bf16(qh[kf], kh, s_acc[nf], 0, 0, 0);
                s_acc[nf] = __builtin_amdgcn_mfma_f32_16x16x32_bf16(qh[kf], kl, s_acc[nf], 0, 0, 0);
                s_acc[nf] = __builtin_amdgcn_mfma_f32_16x16x32_bf16(ql[kf], kh, s_acc[nf], 0, 0, 0);
            }
        }

        // ---- online softmax (fp32, rows = g*4+j) ----
        int diag = (tile == ntiles - 1);
        float sc_[4][4];
        #pragma unroll
        for (int nf = 0; nf < 4; ++nf)
            #pragma unroll
            for (int j = 0; j < 4; ++j) {
                float s = s_acc[nf][j] * scale;
                if (diag) {
                    int kk = kt0 + (nf << 4) + cc;
                    int qq = q0 + (wv << 4) + (g << 2) + j;
                    if (kk > qq) s = -1e30f;
                }
                sc_[nf][j] = s;
            }
        #pragma unroll
        for (int j = 0; j < 4; ++j) {
            float mtj = fmaxf(fmaxf(sc_[0][j], sc_[1][j]), fmaxf(sc_[2][j], sc_[3][j]));
            #pragma unroll
            for (int off = 8; off >= 1; off >>= 1) mtj = fmaxf(mtj, __shfl_xor(mtj, off));
            float mn = fmaxf(m_[j], mtj);
            float al = __expf(m_[j] - mn);
            float ls = 0.f;
            int qloc = (g << 2) + j;
            #pragma unroll
            for (int nf = 0; nf < 4; ++nf) {
                float p = __expf(sc_[nf][j] - mn);
                unsigned pb = bfround(p);
                ls += __builtin_bit_cast(float, pb << 16);
                int kk = (nf << 4) + cc;
                int byte = (wv << 11) + (qloc << 7) + ((kk << 1) ^ ((qloc & 7) << 4));
                *(unsigned short*)((char*)Ps + byte) = (unsigned short)pb;
            }
            #pragma unroll
            for (int off = 8; off >= 1; off >>= 1) ls += __shfl_xor(ls, off);
            l_[j] = l_[j] * al + ls;
            m_[j] = mn;
            #pragma unroll
            for (int nd = 0; nd < 8; ++nd) acc_o[nd][j] *= al;
        }

        // ---- PV: O += P.V  (P A-frags from per-wave LDS; V^T B-frags) ----
        #pragma unroll
        for (int kc = 0; kc < 2; ++kc) {
            int addrp = (wv << 11) + (cc << 7) + ((((kc << 2) + g) ^ (cc & 7)) << 4);
            short8 pa = *(const short8*)((const char*)Ps + addrp);
            #pragma unroll
            for (int nd = 0; nd < 8; ++nd) {
                int dr = (nd << 4) + cc;
                int addr = (dr << 7) + ((((kc << 2) + g) ^ (dr & 7)) << 4);
                short8 vh = *(const short8*)((const char*)Vs_hi + addr);
                short8 vl = *(const short8*)((const char*)Vs_lo + addr);
                acc_o[nd] = __builtin_amdgcn_mfma_f32_16x16x32_bf16(pa, vh, acc_o[nd], 0, 0, 0);
                acc_o[nd] = __builtin_amdgcn_mfma_f32_16x16x32_bf16(pa, vl, acc_o[nd], 0, 0, 0);
            }
        }
    }

    // ---- epilogue: O /= l, store ----
    float inv[4];
    #pragma unroll
    for (int j = 0; j < 4; ++j) inv[j] = 1.0f / l_[j];
    float* abase = att + ((long)(b * T_CTX + q0 + (wv << 4) + (g << 2))) * D + hh * HS;
    #pragma unroll
    for (int nd = 0; nd < 8; ++nd) {
        int d = (nd << 4) + cc;
        #pragma unroll
        for (int j = 0; j < 4; ++j)
            abase[(long)j * D + d] = acc_o[nd][j] * inv[j];
    }
}

// ---------------- launch -------------------------------------------------
extern "C" void kernel_launch(void* const* d_in, const int* in_sizes, int n_in,
                              void* d_out, int out_size, void* d_ws, size_t ws_size,
                              hipStream_t stream) {
    (void)in_sizes; (void)n_in; (void)out_size; (void)ws_size;
    const int*   idx     = (const int*)  d_in[0];
    const float* tok_emb = (const float*)d_in[1];
    const float* pos_emb = (const float*)d_in[2];
    const float* wq      = (const float*)d_in[3];
    const float* wk      = (const float*)d_in[4];
    const float* wv      = (const float*)d_in[5];
    const float* wo      = (const float*)d_in[6];
    const float* bo      = (const float*)d_in[7];
    const float* w1      = (const float*)d_in[8];
    const float* b1      = (const float*)d_in[9];
    const float* w2      = (const float*)d_in[10];
    const float* b2      = (const float*)d_in[11];
    const float* g1      = (const float*)d_in[12];
    const float* be1     = (const float*)d_in[13];
    const float* g2      = (const float*)d_in[14];
    const float* be2     = (const float*)d_in[15];
    const float* wlm     = (const float*)d_in[16];
    const float* blm     = (const float*)d_in[17];
    float* out = (float*)d_out;

    const long SZ = (long)ROWS * D;
    float* ws   = (float*)d_ws;
    float* x    = ws;
    float* h    = ws + SZ;
    float* q    = ws + 2 * SZ;
    float* kbuf = ws + 3 * SZ;
    float* vbuf = ws + 4 * SZ;   // holds V^T: [b][h][d][t]
    float* att  = ws + 5 * SZ;
    float* ff   = q;             // [4096, 3072] reuses q..att

    embed_kernel<<<ROWS, 192, 0, stream>>>(idx, tok_emb, pos_emb, x);

    for (int l = 0; l < NL; ++l) {
        ln_kernel<<<ROWS, 256, 0, stream>>>(x, g1 + l * D, be1 + l * D, h);

        dim3 gq(1, 32, NH);
        const long wsz = (long)NH * D * HS;
        gemm_kernel<<<gq, 256, 0, stream>>>(h, D, wq + (long)l * wsz, HS,
                                            (long)D * HS, q, D, HS,
                                            nullptr, nullptr, D, 0, 0);
        gemm_kernel<<<gq, 256, 0, stream>>>(h, D, wk + (long)l * wsz, HS,
                                            (long)D * HS, kbuf, D, HS,
                                            nullptr, nullptr, D, 0, 0);
        // V projection written transposed: [b][h][d][t]
        gemm_kernel<<<gq, 256, 0, stream>>>(h, D, wv + (long)l * wsz, HS,
                                            (long)D * HS, vbuf, D, 0,
                                            nullptr, nullptr, D, 0, 1);

        attn_kernel<<<dim3(T_CTX / 64, 4 * NH), 256, 0, stream>>>(q, kbuf, vbuf, att);

        gemm_kernel<<<dim3(6, 32, 1), 256, 0, stream>>>(
            att, D, wo + (long)l * D * D, D, 0, x, D, 0,
            bo + l * D, x, D, 0, 0);

        ln_kernel<<<ROWS, 256, 0, stream>>>(x, g2 + l * D, be2 + l * D, h);

        gemm_kernel<<<dim3(24, 32, 1), 256, 0, stream>>>(
            h, D, w1 + (long)l * D * FFD, FFD, 0, ff, FFD, 0,
            b1 + (long)l * FFD, nullptr, D, 1, 0);

        gemm_kernel<<<dim3(6, 32, 1), 256, 0, stream>>>(
            ff, FFD, w2 + (long)l * FFD * D, D, 0, x, D, 0,
            b2 + l * D, x, FFD, 0, 0);
    }

    gemm_kernel<<<dim3(VOCAB / 128, 32, 1), 256, 0, stream>>>(
        x, D, wlm, VOCAB, 0, out, VOCAB, 0, blm, nullptr, D, 0, 0);
}